// Round 2
// 427.888 us; speedup vs baseline: 1.1000x; 1.1000x over previous
//
#include <hip/hip_runtime.h>
#include <hip/hip_bf16.h>

// ELSA block. Inputs: float32. Output: float32. Internal: bf16 (MFMA).
// Pipeline:
//  k_prep: weight repack f32->bf16 (interleave q/k rows, pad, fold ghost, swizzle conv w)
//  k_ln:   LayerNorm, x (B,C,D,H,W) f32 -> xn_t (frame*pix, 96) bf16 [pixel-major]
//  k_gemm<0>: qkv projection (MFMA) -> h=(q*k*scale) (f,c,p), v (f,c,p) bf16 [planar]
//  k_conv: grouped 7x7 conv + exact GELU -> a_t in BLOCKED-4 layout
//          a_t[((f*24+g)*PIX + pix)*4 + co]  (full-line coalesced writes)
//  2 chunks of 8 frames:  k_gemm<1>: 294-ch logits + ghost -> attn_c (8f,294,p)
//                         k_aggr: 49-tap window aggregation -> out_t BLOCKED-4
//  k_gemm<2>: out proj + bias + f32 residual -> d_out f32 (B,C,D,H,W)
// Workspace (bytes), total 128,512,512 (~122.6 MB):
//  [0)        W2 (320x96 bf16)  61,440
//  [61440)    bias2 (320 f32)    1,280
//  [62720)    WA2 (320x96 bf16) 61,440
//  [124160)   biasA2 (320 f32)   1,280
//  [125440)   WP (128x96 bf16)  24,576
//  [150016)   biasP (128 f32)      512
//  [150528)   WC1 (24x4x7x7x4 f32) 75,264
//  [225792)   xn_t / a_t   28,311,552
//  [28537344) h / out_t    28,311,552
//  [56848896) v            28,311,552
//  [85160448) attn_c (8x294x9216 bf16) 43,352,064

typedef unsigned short u16;
typedef short bf16x8 __attribute__((ext_vector_type(8)));
typedef float floatx4 __attribute__((ext_vector_type(4)));
typedef unsigned short ushort8 __attribute__((ext_vector_type(8)));
typedef unsigned short ushort4v __attribute__((ext_vector_type(4)));
typedef unsigned int uint4v __attribute__((ext_vector_type(4)));
typedef unsigned int uint2v __attribute__((ext_vector_type(2)));

#define PIX      9216
#define SCALE_QK 0.25f

__device__ __forceinline__ float b2f(u16 u) {
  union { unsigned int i; float f; } z; z.i = ((unsigned int)u) << 16; return z.f;
}
__device__ __forceinline__ float lo2f(unsigned int u) {
  union { unsigned int i; float f; } z; z.i = u << 16; return z.f;
}
__device__ __forceinline__ float hi2f(unsigned int u) {
  union { unsigned int i; float f; } z; z.i = u & 0xFFFF0000u; return z.f;
}
__device__ __forceinline__ u16 f2b(float f) {
  union { float f; unsigned int i; } z; z.f = f;
  unsigned int r = z.i + 0x7fffu + ((z.i >> 16) & 1u);
  return (u16)(r >> 16);
}

// ---------------- weight prep (f32 in, bf16/f32 out) ----------------
__global__ void k_prep(const float* __restrict__ w_qk, const float* __restrict__ b_qk,
                       const float* __restrict__ w_v,  const float* __restrict__ b_v,
                       const float* __restrict__ w_a1,
                       const float* __restrict__ w_a2, const float* __restrict__ b_a2,
                       const float* __restrict__ g_mul,const float* __restrict__ g_add,
                       const float* __restrict__ w_p,  const float* __restrict__ b_p,
                       u16* __restrict__ W2, float* __restrict__ bias2,
                       u16* __restrict__ WA2, float* __restrict__ biasA2,
                       u16* __restrict__ WP, float* __restrict__ biasP,
                       float* __restrict__ WC1) {
  int i = blockIdx.x * 256 + threadIdx.x;
  if (i < 30720) {                       // W2: 320*96
    int r = i / 96, ci = i % 96;
    float val = 0.f;
    if (r < 192) { int src = (r & 1) ? (96 + (r >> 1)) : (r >> 1); val = w_qk[src * 96 + ci]; }
    else if (r < 288) val = w_v[(r - 192) * 96 + ci];
    W2[i] = f2b(val);
  } else if (i < 31040) {                // bias2: 320
    int r = i - 30720; float bv = 0.f;
    if (r < 192) { int src = (r & 1) ? (96 + (r >> 1)) : (r >> 1); bv = b_qk[src]; }
    else if (r < 288) bv = b_v[r - 192];
    bias2[r] = bv;
  } else if (i < 61760) {                // WA2: 320*96
    int j = i - 31040; int r = j / 96, ci = j % 96;
    float wv = 0.f;
    if (r < 294) wv = w_a2[r * 96 + ci] * g_mul[r];
    WA2[j] = f2b(wv);
  } else if (i < 62080) {                // biasA2: 320
    int r = i - 61760; float bv = 0.f;
    if (r < 294) bv = b_a2[r] * g_mul[r] + g_add[r];
    biasA2[r] = bv;
  } else if (i < 74368) {                // WP: 128*96
    int j = i - 62080; int r = j / 96;
    WP[j] = (r < 96) ? f2b(w_p[j]) : (u16)0;
  } else if (i < 74496) {                // biasP: 128
    int r = i - 74368;
    biasP[r] = (r < 96) ? b_p[r] : 0.f;
  } else if (i < 93312) {                // WC1: [g][ch][ky][kx][co] f32, 18816
    int j = i - 74496;
    int co = j & 3, kx = (j >> 2) % 7, ky = (j / 28) % 7, ch = (j / 196) & 3, g = j / 784;
    WC1[j] = w_a1[(g * 4 + co) * 196 + ch * 49 + ky * 7 + kx];
  }
}

// ---------------- LayerNorm ----------------
__global__ __launch_bounds__(256) void k_ln(const float* __restrict__ x,
                                            const float* __restrict__ lg,
                                            const float* __restrict__ lb,
                                            u16* __restrict__ xn) {
  int idx = blockIdx.x * 256 + threadIdx.x;    // 0..147455
  int f = idx / PIX, p = idx % PIX;
  int b = f >> 3, d = f & 7;
  size_t base = ((size_t)(b * 768 + d)) * PIX + p;  // + c*73728
  float s = 0.f, ss = 0.f;
  for (int c = 0; c < 96; ++c) {
    float v = x[base + (size_t)c * 73728];
    s += v; ss += v * v;
  }
  float mu = s * (1.f / 96.f);
  float var = ss * (1.f / 96.f) - mu * mu;
  float rs = rsqrtf(var + 1e-5f);
  size_t ob = (size_t)idx * 96;
  for (int c0 = 0; c0 < 96; c0 += 8) {
    ushort8 pack;
    for (int u = 0; u < 8; ++u) {
      int c = c0 + u;
      float v = x[base + (size_t)c * 73728];
      pack[u] = f2b((v - mu) * rs * lg[c] + lb[c]);
    }
    *(ushort8*)&xn[ob + c0] = pack;
  }
}

// ---------------- MFMA GEMM (64co x 64p tile, K=96) ----------------
// MODE 0: qkv -> h (out0), v (out1), f = blockIdx.z. X = xn_t (pixel-major 96).
// MODE 1: attn chunk (out0, f = fArg + blockIdx.z, store frame-local z). X = a_t BLOCKED-4.
// MODE 2: final f32 (outF = d_out), resid = x f32, f = blockIdx.z. X = out_t BLOCKED-4.
template <int MODE>
__global__ __launch_bounds__(256) void k_gemm(const u16* __restrict__ X,
                                              const u16* __restrict__ W,
                                              const float* __restrict__ bias,
                                              u16* __restrict__ out0,
                                              u16* __restrict__ out1,
                                              float* __restrict__ outF,
                                              const float* __restrict__ resid,
                                              int fArg) {
  __shared__ u16 lw[64 * 104];
  __shared__ u16 lx[64 * 104];
  const int tid = threadIdx.x;
  const int fc = blockIdx.z;
  const int f = (MODE == 1) ? (fArg + fc) : fc;
  const int p0 = blockIdx.x * 64;
  const int cot = blockIdx.y;

  if constexpr (MODE == 0) {
    for (int ch = tid; ch < 768; ch += 256) {
      int r = ch / 12, s2 = ch % 12;
      *(uint4v*)&lw[r * 104 + s2 * 8] = *(const uint4v*)&W[(size_t)(cot * 64 + r) * 96 + s2 * 8];
      *(uint4v*)&lx[r * 104 + s2 * 8] = *(const uint4v*)&X[((size_t)(f * PIX + p0 + r)) * 96 + s2 * 8];
    }
  } else {
    for (int ch = tid; ch < 768; ch += 256) {
      int r = ch / 12, s2 = ch % 12;
      *(uint4v*)&lw[r * 104 + s2 * 8] = *(const uint4v*)&W[(size_t)(cot * 64 + r) * 96 + s2 * 8];
    }
    // X is blocked-4: X[((f*24 + g)*PIX + p)*4 + co]. Channel-oct s2 spans
    // groups 2*s2, 2*s2+1. r fastest across lanes -> contiguous 8B reads.
    for (int idx = tid; idx < 768; idx += 256) {
      int s2 = idx >> 6, r = idx & 63;
      const u16* src0 = &X[((size_t)(f * 24 + 2 * s2) * PIX + p0 + r) * 4];
      const u16* src1 = &X[((size_t)(f * 24 + 2 * s2 + 1) * PIX + p0 + r) * 4];
      *(uint2v*)&lx[r * 104 + s2 * 8]     = *(const uint2v*)src0;
      *(uint2v*)&lx[r * 104 + s2 * 8 + 4] = *(const uint2v*)src1;
    }
  }
  __syncthreads();

  const int lane = tid & 63, wv = tid >> 6;
  const int cw = (wv >> 1) * 32, pw = (wv & 1) * 32;
  const int m = lane & 15, quad = lane >> 4;

  floatx4 acc[2][2] = {};
  for (int ks = 0; ks < 3; ++ks) {
    int ko = ks * 32 + quad * 8;
    bf16x8 a0 = *(const bf16x8*)&lw[(cw + m) * 104 + ko];
    bf16x8 a1 = *(const bf16x8*)&lw[(cw + 16 + m) * 104 + ko];
    bf16x8 b0 = *(const bf16x8*)&lx[(pw + m) * 104 + ko];
    bf16x8 b1 = *(const bf16x8*)&lx[(pw + 16 + m) * 104 + ko];
    acc[0][0] = __builtin_amdgcn_mfma_f32_16x16x32_bf16(a0, b0, acc[0][0], 0, 0, 0);
    acc[0][1] = __builtin_amdgcn_mfma_f32_16x16x32_bf16(a0, b1, acc[0][1], 0, 0, 0);
    acc[1][0] = __builtin_amdgcn_mfma_f32_16x16x32_bf16(a1, b0, acc[1][0], 0, 0, 0);
    acc[1][1] = __builtin_amdgcn_mfma_f32_16x16x32_bf16(a1, b1, acc[1][1], 0, 0, 0);
  }

  for (int mt = 0; mt < 2; ++mt)
    for (int nt = 0; nt < 2; ++nt) {
      int R = cot * 64 + cw + mt * 16 + quad * 4;
      int pc = p0 + pw + nt * 16 + m;
      floatx4 v4 = acc[mt][nt];
      if (MODE == 0) {
        if (cot < 3) {
          float q0 = v4[0] + bias[R + 0], k0 = v4[1] + bias[R + 1];
          float q1 = v4[2] + bias[R + 2], k1 = v4[3] + bias[R + 3];
          int hc = R >> 1;
          out0[((size_t)f * 96 + hc) * PIX + pc]     = f2b(q0 * k0 * SCALE_QK);
          out0[((size_t)f * 96 + hc + 1) * PIX + pc] = f2b(q1 * k1 * SCALE_QK);
        } else {
          for (int r = 0; r < 4; ++r) {
            int vr = R + r - 192;
            if (vr < 96) out1[((size_t)f * 96 + vr) * PIX + pc] = f2b(v4[r] + bias[R + r]);
          }
        }
      } else if (MODE == 1) {
        for (int r = 0; r < 4; ++r) {
          int o = R + r;
          if (o < 294) out0[((size_t)fc * 294 + o) * PIX + pc] = f2b(v4[r] + bias[o]);
        }
      } else {
        int b = f >> 3, d = f & 7;
        for (int r = 0; r < 4; ++r) {
          int o = R + r;
          if (o < 96) {
            size_t gi = ((size_t)(b * 96 + o) * 8 + d) * PIX + pc;
            outF[gi] = resid[gi] + v4[r] + bias[o];
          }
        }
      }
    }
}

// ---------------- grouped 7x7 conv + GELU (sliding window, bf16 LDS) ----------
// h: (f, 96, 9216) bf16 -> a_t BLOCKED-4: a_t[((f*24+g)*PIX + pix)*4 + co].
// block = (group g of 4 ch, 32-row tile, frame). thread = (y of 32, xseg of 12).
// launch_bounds(256,4): allow 128 VGPRs (acc[4][12]+in[18] live) -- no spill.
__global__ __launch_bounds__(256, 4) void k_conv(const u16* __restrict__ h,
                                                 const float* __restrict__ wc1,
                                                 const float* __restrict__ b_a1,
                                                 u16* __restrict__ a_t) {
  __shared__ u16 li[4 * 38 * 104];   // 4 ch x rows y0-3..y0+34 x cols -3..100, 31.6KB
  const int g = blockIdx.x, ty = blockIdx.y, f = blockIdx.z;
  const int tid = threadIdx.x;
  const int gb = g * 4, y0 = ty * 32;
  for (int idx = tid; idx < 4 * 38 * 104; idx += 256) {
    int col = idx % 104;
    int rr = (idx / 104) % 38;
    int ch = idx / (104 * 38);
    int ax = col - 3, ay = y0 - 3 + rr;
    u16 v = 0;
    if (ax >= 0 && ax < 96 && ay >= 0 && ay < 96)
      v = h[((size_t)f * 96 + gb + ch) * PIX + ay * 96 + ax];
    li[idx] = v;
  }
  __syncthreads();

  const int y = tid >> 3;            // 0..31
  const int x0 = (tid & 7) * 12;     // 0..84 (even -> dword-aligned LDS reads)
  float acc[4][12];
  #pragma unroll
  for (int co = 0; co < 4; ++co) {
    float bv = b_a1[gb + co];
    #pragma unroll
    for (int o = 0; o < 12; ++o) acc[co][o] = bv;
  }

  for (int ch = 0; ch < 4; ++ch)
    for (int ky = 0; ky < 7; ++ky) {
      const float* wrow = &wc1[(((g * 4 + ch) * 7) + ky) * 28];
      float w[28];
      #pragma unroll
      for (int t = 0; t < 28; ++t) w[t] = wrow[t];
      const unsigned int* lsrc =
          (const unsigned int*)&li[(ch * 38 + (y + ky)) * 104 + x0];
      float in[18];
      #pragma unroll
      for (int t = 0; t < 9; ++t) {
        unsigned int u = lsrc[t];
        in[2 * t]     = lo2f(u);
        in[2 * t + 1] = hi2f(u);
      }
      #pragma unroll
      for (int kx = 0; kx < 7; ++kx)
        #pragma unroll
        for (int o = 0; o < 12; ++o)
          #pragma unroll
          for (int co = 0; co < 4; ++co)
            acc[co][o] += w[kx * 4 + co] * in[o + kx];
    }

  // blocked-4 store: 96B contiguous per thread, full-line coalesced per wave.
  size_t obase = ((size_t)(f * 24 + g) * PIX + (size_t)(y0 + y) * 96 + x0) * 4;
  #pragma unroll
  for (int o = 0; o < 12; o += 2) {
    ushort8 r8;
    #pragma unroll
    for (int co = 0; co < 4; ++co) {
      float a0 = acc[co][o], a1 = acc[co][o + 1];
      r8[co]     = f2b(0.5f * a0 * (1.f + erff(a0 * 0.70710678118f)));
      r8[co + 4] = f2b(0.5f * a1 * (1.f + erff(a1 * 0.70710678118f)));
    }
    *(ushort8*)&a_t[obase + o * 4] = r8;
  }
}

// ---------------- 49-tap window aggregation (8-frame chunk) ----------------
// attn_c: (8, 294, 9216) bf16, v: (f, 96, 9216) bf16 -> out_t BLOCKED-4:
// out_t[((f*24+cq)*PIX + pix)*4 + ch].
// block = (cquad of 4 ch, 16-row tile, frame-in-chunk).
__global__ __launch_bounds__(256, 4) void k_aggr(const u16* __restrict__ attn_c,
                                                 const u16* __restrict__ v,
                                                 u16* __restrict__ out_t,
                                                 int fbase) {
  __shared__ u16 lv[4 * 22 * 104];   // 18.3KB
  const int cq = blockIdx.x, ty = blockIdx.y, fc = blockIdx.z;
  const int f = fbase + fc;
  const int tid = threadIdx.x;
  const int c0 = cq * 4, y0 = ty * 16;
  const int head = c0 >> 4;
  for (int idx = tid; idx < 4 * 22 * 104; idx += 256) {
    int col = idx % 104;
    int rr = (idx / 104) % 22;
    int ch = idx / (104 * 22);
    int ax = col - 3, ay = y0 - 3 + rr;
    u16 val = 0;
    if (ax >= 0 && ax < 96 && ay >= 0 && ay < 96)
      val = v[((size_t)f * 96 + c0 + ch) * PIX + ay * 96 + ax];
    lv[idx] = val;
  }
  __syncthreads();

  const int y = tid >> 4;            // 0..15
  const int x0 = (tid & 15) * 6;     // 0..90
  float acc[4][6] = {};
  const int prow = (y0 + y) * 96 + x0;

  for (int i = 0; i < 7; ++i) {
    float vrow[4][12];
    #pragma unroll
    for (int ch = 0; ch < 4; ++ch) {
      const unsigned int* lsrc = (const unsigned int*)&lv[(ch * 22 + (y + i)) * 104 + x0];
      #pragma unroll
      for (int t = 0; t < 6; ++t) {
        unsigned int u = lsrc[t];
        vrow[ch][2 * t]     = lo2f(u);
        vrow[ch][2 * t + 1] = hi2f(u);
      }
    }
    #pragma unroll
    for (int j = 0; j < 7; ++j) {
      const unsigned int* asrc = (const unsigned int*)
          &attn_c[((size_t)fc * 294 + head * 49 + i * 7 + j) * PIX + prow];
      unsigned int u0 = asrc[0], u1 = asrc[1], u2 = asrc[2];
      float av[6] = {lo2f(u0), hi2f(u0), lo2f(u1), hi2f(u1), lo2f(u2), hi2f(u2)};
      #pragma unroll
      for (int o = 0; o < 6; ++o)
        #pragma unroll
        for (int ch = 0; ch < 4; ++ch)
          acc[ch][o] += av[o] * vrow[ch][o + j];
    }
  }

  // blocked-4 store: 48B contiguous per thread.
  size_t obase = ((size_t)(f * 24 + cq) * PIX + prow) * 4;
  #pragma unroll
  for (int o = 0; o < 6; o += 2) {
    ushort8 r8;
    #pragma unroll
    for (int ch = 0; ch < 4; ++ch) {
      r8[ch]     = f2b(acc[ch][o]);
      r8[ch + 4] = f2b(acc[ch][o + 1]);
    }
    *(ushort8*)&out_t[obase + o * 4] = r8;
  }
}

extern "C" void kernel_launch(void* const* d_in, const int* in_sizes, int n_in,
                              void* d_out, int out_size, void* d_ws, size_t ws_size,
                              hipStream_t stream) {
  const float* x    = (const float*)d_in[0];
  const float* ln_g = (const float*)d_in[1];
  const float* ln_b = (const float*)d_in[2];
  const float* w_qk = (const float*)d_in[3];
  const float* b_qk = (const float*)d_in[4];
  const float* w_v  = (const float*)d_in[5];
  const float* b_v  = (const float*)d_in[6];
  const float* w_a1 = (const float*)d_in[7];
  const float* b_a1 = (const float*)d_in[8];
  const float* w_a2 = (const float*)d_in[9];
  const float* b_a2 = (const float*)d_in[10];
  const float* g_mul= (const float*)d_in[11];
  const float* g_add= (const float*)d_in[12];
  const float* w_p  = (const float*)d_in[13];
  const float* b_p  = (const float*)d_in[14];

  char* ws = (char*)d_ws;
  u16*   W2    = (u16*)(ws + 0);
  float* bias2 = (float*)(ws + 61440);
  u16*   WA2   = (u16*)(ws + 62720);
  float* biasA2= (float*)(ws + 124160);
  u16*   WP    = (u16*)(ws + 125440);
  float* biasP = (float*)(ws + 150016);
  float* WC1   = (float*)(ws + 150528);
  u16*   xn_t  = (u16*)(ws + 225792);       // reused as a_t
  u16*   hbuf  = (u16*)(ws + 28537344);     // reused as out_t
  u16*   vbuf  = (u16*)(ws + 56848896);
  u16*   attnc = (u16*)(ws + 85160448);     // 8-frame attn chunk (8 x 294 x 9216)

  k_prep<<<365, 256, 0, stream>>>(w_qk, b_qk, w_v, b_v, w_a1, w_a2, b_a2, g_mul, g_add,
                                  w_p, b_p, W2, bias2, WA2, biasA2, WP, biasP, WC1);
  k_ln<<<576, 256, 0, stream>>>(x, ln_g, ln_b, xn_t);
  k_gemm<0><<<dim3(144, 5, 16), 256, 0, stream>>>(xn_t, W2, bias2, hbuf, vbuf,
                                                  nullptr, nullptr, 0);
  k_conv<<<dim3(24, 3, 16), 256, 0, stream>>>(hbuf, WC1, b_a1, xn_t /*a_t*/);
  for (int c = 0; c < 2; ++c) {
    k_gemm<1><<<dim3(144, 5, 8), 256, 0, stream>>>(xn_t /*a_t*/, WA2, biasA2,
                                                   attnc, nullptr, nullptr, nullptr, c * 8);
    k_aggr<<<dim3(24, 6, 8), 256, 0, stream>>>(attnc, vbuf, hbuf /*out_t*/, c * 8);
  }
  k_gemm<2><<<dim3(144, 2, 16), 256, 0, stream>>>(hbuf /*out_t*/, WP, biasP,
                                                  nullptr, nullptr, (float*)d_out, x, 0);
}

// Round 3
// 408.254 us; speedup vs baseline: 1.1529x; 1.0481x over previous
//
#include <hip/hip_runtime.h>
#include <hip/hip_bf16.h>

// ELSA block. Inputs: float32. Output: float32. Internal: bf16 (MFMA).
// Pipeline:
//  k_prep: weight repack f32->bf16 (interleave q/k rows, pad, fold ghost, swizzle conv w)
//  k_ln:   LayerNorm, x (B,C,D,H,W) f32 -> xn_t (frame*pix, 96) bf16 [pixel-major]
//  k_gemm<0>: qkv projection (MFMA) -> h=(q*k*scale) (f,c,p), v (f,c,p) bf16 [planar]
//  k_conv: grouped 7x7 conv + exact GELU -> a_t in BLOCKED-4 layout
//          a_t[((f*24+g)*PIX + pix)*4 + co]  (full-line coalesced writes)
//          16-row tiles (grid 2304, LDS 18.3KB) for occupancy.
//  2 chunks of 8 frames:  k_gemm<1>: 294-ch logits + ghost -> attn_c (8f,294,p)
//                         k_aggr: 49-tap window aggregation -> out_t BLOCKED-4
//                                 (XCD-swizzled: 4 cquads of a head co-resident)
//  k_gemm<2>: out proj + bias + f32 residual -> d_out f32 (B,C,D,H,W)
// Workspace (bytes), total 128,512,512 (~122.6 MB):
//  [0)        W2 (320x96 bf16)  61,440
//  [61440)    bias2 (320 f32)    1,280
//  [62720)    WA2 (320x96 bf16) 61,440
//  [124160)   biasA2 (320 f32)   1,280
//  [125440)   WP (128x96 bf16)  24,576
//  [150016)   biasP (128 f32)      512
//  [150528)   WC1 (24x4x7x7x4 f32) 75,264
//  [225792)   xn_t / a_t   28,311,552
//  [28537344) h / out_t    28,311,552
//  [56848896) v            28,311,552
//  [85160448) attn_c (8x294x9216 bf16) 43,352,064

typedef unsigned short u16;
typedef short bf16x8 __attribute__((ext_vector_type(8)));
typedef float floatx4 __attribute__((ext_vector_type(4)));
typedef unsigned short ushort8 __attribute__((ext_vector_type(8)));
typedef unsigned short ushort4v __attribute__((ext_vector_type(4)));
typedef unsigned int uint4v __attribute__((ext_vector_type(4)));
typedef unsigned int uint2v __attribute__((ext_vector_type(2)));

#define PIX      9216
#define SCALE_QK 0.25f

__device__ __forceinline__ float b2f(u16 u) {
  union { unsigned int i; float f; } z; z.i = ((unsigned int)u) << 16; return z.f;
}
__device__ __forceinline__ float lo2f(unsigned int u) {
  union { unsigned int i; float f; } z; z.i = u << 16; return z.f;
}
__device__ __forceinline__ float hi2f(unsigned int u) {
  union { unsigned int i; float f; } z; z.i = u & 0xFFFF0000u; return z.f;
}
__device__ __forceinline__ u16 f2b(float f) {
  union { float f; unsigned int i; } z; z.f = f;
  unsigned int r = z.i + 0x7fffu + ((z.i >> 16) & 1u);
  return (u16)(r >> 16);
}

// ---------------- weight prep (f32 in, bf16/f32 out) ----------------
__global__ void k_prep(const float* __restrict__ w_qk, const float* __restrict__ b_qk,
                       const float* __restrict__ w_v,  const float* __restrict__ b_v,
                       const float* __restrict__ w_a1,
                       const float* __restrict__ w_a2, const float* __restrict__ b_a2,
                       const float* __restrict__ g_mul,const float* __restrict__ g_add,
                       const float* __restrict__ w_p,  const float* __restrict__ b_p,
                       u16* __restrict__ W2, float* __restrict__ bias2,
                       u16* __restrict__ WA2, float* __restrict__ biasA2,
                       u16* __restrict__ WP, float* __restrict__ biasP,
                       float* __restrict__ WC1) {
  int i = blockIdx.x * 256 + threadIdx.x;
  if (i < 30720) {                       // W2: 320*96
    int r = i / 96, ci = i % 96;
    float val = 0.f;
    if (r < 192) { int src = (r & 1) ? (96 + (r >> 1)) : (r >> 1); val = w_qk[src * 96 + ci]; }
    else if (r < 288) val = w_v[(r - 192) * 96 + ci];
    W2[i] = f2b(val);
  } else if (i < 31040) {                // bias2: 320
    int r = i - 30720; float bv = 0.f;
    if (r < 192) { int src = (r & 1) ? (96 + (r >> 1)) : (r >> 1); bv = b_qk[src]; }
    else if (r < 288) bv = b_v[r - 192];
    bias2[r] = bv;
  } else if (i < 61760) {                // WA2: 320*96
    int j = i - 31040; int r = j / 96, ci = j % 96;
    float wv = 0.f;
    if (r < 294) wv = w_a2[r * 96 + ci] * g_mul[r];
    WA2[j] = f2b(wv);
  } else if (i < 62080) {                // biasA2: 320
    int r = i - 61760; float bv = 0.f;
    if (r < 294) bv = b_a2[r] * g_mul[r] + g_add[r];
    biasA2[r] = bv;
  } else if (i < 74368) {                // WP: 128*96
    int j = i - 62080; int r = j / 96;
    WP[j] = (r < 96) ? f2b(w_p[j]) : (u16)0;
  } else if (i < 74496) {                // biasP: 128
    int r = i - 74368;
    biasP[r] = (r < 96) ? b_p[r] : 0.f;
  } else if (i < 93312) {                // WC1: [g][ch][ky][kx][co] f32, 18816
    int j = i - 74496;
    int co = j & 3, kx = (j >> 2) % 7, ky = (j / 28) % 7, ch = (j / 196) & 3, g = j / 784;
    WC1[j] = w_a1[(g * 4 + co) * 196 + ch * 49 + ky * 7 + kx];
  }
}

// ---------------- LayerNorm ----------------
__global__ __launch_bounds__(256) void k_ln(const float* __restrict__ x,
                                            const float* __restrict__ lg,
                                            const float* __restrict__ lb,
                                            u16* __restrict__ xn) {
  int idx = blockIdx.x * 256 + threadIdx.x;    // 0..147455
  int f = idx / PIX, p = idx % PIX;
  int b = f >> 3, d = f & 7;
  size_t base = ((size_t)(b * 768 + d)) * PIX + p;  // + c*73728
  float s = 0.f, ss = 0.f;
  for (int c = 0; c < 96; ++c) {
    float v = x[base + (size_t)c * 73728];
    s += v; ss += v * v;
  }
  float mu = s * (1.f / 96.f);
  float var = ss * (1.f / 96.f) - mu * mu;
  float rs = rsqrtf(var + 1e-5f);
  size_t ob = (size_t)idx * 96;
  for (int c0 = 0; c0 < 96; c0 += 8) {
    ushort8 pack;
    for (int u = 0; u < 8; ++u) {
      int c = c0 + u;
      float v = x[base + (size_t)c * 73728];
      pack[u] = f2b((v - mu) * rs * lg[c] + lb[c]);
    }
    *(ushort8*)&xn[ob + c0] = pack;
  }
}

// ---------------- MFMA GEMM (64co x 64p tile, K=96) ----------------
// MODE 0: qkv -> h (out0), v (out1), f = blockIdx.z. X = xn_t (pixel-major 96).
// MODE 1: attn chunk (out0, f = fArg + blockIdx.z, store frame-local z). X = a_t BLOCKED-4.
// MODE 2: final f32 (outF = d_out), resid = x f32, f = blockIdx.z. X = out_t BLOCKED-4.
template <int MODE>
__global__ __launch_bounds__(256) void k_gemm(const u16* __restrict__ X,
                                              const u16* __restrict__ W,
                                              const float* __restrict__ bias,
                                              u16* __restrict__ out0,
                                              u16* __restrict__ out1,
                                              float* __restrict__ outF,
                                              const float* __restrict__ resid,
                                              int fArg) {
  __shared__ u16 lw[64 * 104];
  __shared__ u16 lx[64 * 104];
  const int tid = threadIdx.x;
  const int fc = blockIdx.z;
  const int f = (MODE == 1) ? (fArg + fc) : fc;
  const int p0 = blockIdx.x * 64;
  const int cot = blockIdx.y;

  if constexpr (MODE == 0) {
    for (int ch = tid; ch < 768; ch += 256) {
      int r = ch / 12, s2 = ch % 12;
      *(uint4v*)&lw[r * 104 + s2 * 8] = *(const uint4v*)&W[(size_t)(cot * 64 + r) * 96 + s2 * 8];
      *(uint4v*)&lx[r * 104 + s2 * 8] = *(const uint4v*)&X[((size_t)(f * PIX + p0 + r)) * 96 + s2 * 8];
    }
  } else {
    for (int ch = tid; ch < 768; ch += 256) {
      int r = ch / 12, s2 = ch % 12;
      *(uint4v*)&lw[r * 104 + s2 * 8] = *(const uint4v*)&W[(size_t)(cot * 64 + r) * 96 + s2 * 8];
    }
    // X is blocked-4: X[((f*24 + g)*PIX + p)*4 + co]. Channel-oct s2 spans
    // groups 2*s2, 2*s2+1. r fastest across lanes -> contiguous 8B reads.
    for (int idx = tid; idx < 768; idx += 256) {
      int s2 = idx >> 6, r = idx & 63;
      const u16* src0 = &X[((size_t)(f * 24 + 2 * s2) * PIX + p0 + r) * 4];
      const u16* src1 = &X[((size_t)(f * 24 + 2 * s2 + 1) * PIX + p0 + r) * 4];
      *(uint2v*)&lx[r * 104 + s2 * 8]     = *(const uint2v*)src0;
      *(uint2v*)&lx[r * 104 + s2 * 8 + 4] = *(const uint2v*)src1;
    }
  }
  __syncthreads();

  const int lane = tid & 63, wv = tid >> 6;
  const int cw = (wv >> 1) * 32, pw = (wv & 1) * 32;
  const int m = lane & 15, quad = lane >> 4;

  floatx4 acc[2][2] = {};
  for (int ks = 0; ks < 3; ++ks) {
    int ko = ks * 32 + quad * 8;
    bf16x8 a0 = *(const bf16x8*)&lw[(cw + m) * 104 + ko];
    bf16x8 a1 = *(const bf16x8*)&lw[(cw + 16 + m) * 104 + ko];
    bf16x8 b0 = *(const bf16x8*)&lx[(pw + m) * 104 + ko];
    bf16x8 b1 = *(const bf16x8*)&lx[(pw + 16 + m) * 104 + ko];
    acc[0][0] = __builtin_amdgcn_mfma_f32_16x16x32_bf16(a0, b0, acc[0][0], 0, 0, 0);
    acc[0][1] = __builtin_amdgcn_mfma_f32_16x16x32_bf16(a0, b1, acc[0][1], 0, 0, 0);
    acc[1][0] = __builtin_amdgcn_mfma_f32_16x16x32_bf16(a1, b0, acc[1][0], 0, 0, 0);
    acc[1][1] = __builtin_amdgcn_mfma_f32_16x16x32_bf16(a1, b1, acc[1][1], 0, 0, 0);
  }

  for (int mt = 0; mt < 2; ++mt)
    for (int nt = 0; nt < 2; ++nt) {
      int R = cot * 64 + cw + mt * 16 + quad * 4;
      int pc = p0 + pw + nt * 16 + m;
      floatx4 v4 = acc[mt][nt];
      if (MODE == 0) {
        if (cot < 3) {
          float q0 = v4[0] + bias[R + 0], k0 = v4[1] + bias[R + 1];
          float q1 = v4[2] + bias[R + 2], k1 = v4[3] + bias[R + 3];
          int hc = R >> 1;
          out0[((size_t)f * 96 + hc) * PIX + pc]     = f2b(q0 * k0 * SCALE_QK);
          out0[((size_t)f * 96 + hc + 1) * PIX + pc] = f2b(q1 * k1 * SCALE_QK);
        } else {
          for (int r = 0; r < 4; ++r) {
            int vr = R + r - 192;
            if (vr < 96) out1[((size_t)f * 96 + vr) * PIX + pc] = f2b(v4[r] + bias[R + r]);
          }
        }
      } else if (MODE == 1) {
        for (int r = 0; r < 4; ++r) {
          int o = R + r;
          if (o < 294) out0[((size_t)fc * 294 + o) * PIX + pc] = f2b(v4[r] + bias[o]);
        }
      } else {
        int b = f >> 3, d = f & 7;
        for (int r = 0; r < 4; ++r) {
          int o = R + r;
          if (o < 96) {
            size_t gi = ((size_t)(b * 96 + o) * 8 + d) * PIX + pc;
            outF[gi] = resid[gi] + v4[r] + bias[o];
          }
        }
      }
    }
}

// ---------------- grouped 7x7 conv + GELU (sliding window, bf16 LDS) ----------
// h: (f, 96, 9216) bf16 -> a_t BLOCKED-4: a_t[((f*24+g)*PIX + pix)*4 + co].
// block = (group g of 4 ch, 16-row tile, frame). thread = (y of 16, xseg of 6).
// LDS 18.3KB -> 8 blocks/CU; grid 2304 -> ~9 blocks/CU avail. Occupancy fix.
__global__ __launch_bounds__(256, 4) void k_conv(const u16* __restrict__ h,
                                                 const float* __restrict__ wc1,
                                                 const float* __restrict__ b_a1,
                                                 u16* __restrict__ a_t) {
  __shared__ u16 li[4 * 22 * 104];   // 4 ch x rows y0-3..y0+18 x cols -3..100, 18.3KB
  const int g = blockIdx.x, ty = blockIdx.y, f = blockIdx.z;
  const int tid = threadIdx.x;
  const int gb = g * 4, y0 = ty * 16;
  for (int idx = tid; idx < 4 * 22 * 104; idx += 256) {
    int col = idx % 104;
    int rr = (idx / 104) % 22;
    int ch = idx / (104 * 22);
    int ax = col - 3, ay = y0 - 3 + rr;
    u16 v = 0;
    if (ax >= 0 && ax < 96 && ay >= 0 && ay < 96)
      v = h[((size_t)f * 96 + gb + ch) * PIX + ay * 96 + ax];
    li[idx] = v;
  }
  __syncthreads();

  const int y = tid >> 4;            // 0..15
  const int x0 = (tid & 15) * 6;     // 0..90 (even -> dword-aligned LDS reads)
  float acc[4][6];
  #pragma unroll
  for (int co = 0; co < 4; ++co) {
    float bv = b_a1[gb + co];
    #pragma unroll
    for (int o = 0; o < 6; ++o) acc[co][o] = bv;
  }

  for (int ch = 0; ch < 4; ++ch)
    for (int ky = 0; ky < 7; ++ky) {
      const float* wrow = &wc1[(((g * 4 + ch) * 7) + ky) * 28];
      float w[28];
      #pragma unroll
      for (int t = 0; t < 28; ++t) w[t] = wrow[t];
      const unsigned int* lsrc =
          (const unsigned int*)&li[(ch * 22 + (y + ky)) * 104 + x0];
      float in[12];
      #pragma unroll
      for (int t = 0; t < 6; ++t) {
        unsigned int u = lsrc[t];
        in[2 * t]     = lo2f(u);
        in[2 * t + 1] = hi2f(u);
      }
      #pragma unroll
      for (int kx = 0; kx < 7; ++kx)
        #pragma unroll
        for (int o = 0; o < 6; ++o)
          #pragma unroll
          for (int co = 0; co < 4; ++co)
            acc[co][o] += w[kx * 4 + co] * in[o + kx];
    }

  // blocked-4 store: 48B contiguous per thread, full-line coalesced per wave.
  size_t obase = ((size_t)(f * 24 + g) * PIX + (size_t)(y0 + y) * 96 + x0) * 4;
  #pragma unroll
  for (int o = 0; o < 6; o += 2) {
    ushort8 r8;
    #pragma unroll
    for (int co = 0; co < 4; ++co) {
      float a0 = acc[co][o], a1 = acc[co][o + 1];
      r8[co]     = f2b(0.5f * a0 * (1.f + erff(a0 * 0.70710678118f)));
      r8[co + 4] = f2b(0.5f * a1 * (1.f + erff(a1 * 0.70710678118f)));
    }
    *(ushort8*)&a_t[obase + o * 4] = r8;
  }
}

// ---------------- 49-tap window aggregation (8-frame chunk) ----------------
// attn_c: (8, 294, 9216) bf16, v: (f, 96, 9216) bf16 -> out_t BLOCKED-4:
// out_t[((f*24+cq)*PIX + pix)*4 + ch].
// XCD swizzle: the 4 cquads sharing one head's 49 attn planes get the same
// wgid%8 (same XCD under round-robin dispatch) and adjacent dispatch slots,
// so attn_c re-reads hit that XCD's L2 instead of HBM (4x fetch cut).
// Bijection: 1152 = 8 xcd * 4 member * 36 slot.
__global__ __launch_bounds__(256, 4) void k_aggr(const u16* __restrict__ attn_c,
                                                 const u16* __restrict__ v,
                                                 u16* __restrict__ out_t,
                                                 int fbase) {
  __shared__ u16 lv[4 * 22 * 104];   // 18.3KB
  const int wgid = blockIdx.x + 24 * (blockIdx.y + 6 * blockIdx.z);
  const int xcd = wgid & 7;
  const int member = (wgid >> 3) & 3;
  const int slot = wgid >> 5;
  const int gidx = slot * 8 + xcd;       // 0..287
  const int cqh = gidx % 6;
  const int ty = (gidx / 6) % 6;
  const int fc = gidx / 36;
  const int cq = cqh * 4 + member;
  const int f = fbase + fc;
  const int tid = threadIdx.x;
  const int c0 = cq * 4, y0 = ty * 16;
  const int head = c0 >> 4;
  for (int idx = tid; idx < 4 * 22 * 104; idx += 256) {
    int col = idx % 104;
    int rr = (idx / 104) % 22;
    int ch = idx / (104 * 22);
    int ax = col - 3, ay = y0 - 3 + rr;
    u16 val = 0;
    if (ax >= 0 && ax < 96 && ay >= 0 && ay < 96)
      val = v[((size_t)f * 96 + c0 + ch) * PIX + ay * 96 + ax];
    lv[idx] = val;
  }
  __syncthreads();

  const int y = tid >> 4;            // 0..15
  const int x0 = (tid & 15) * 6;     // 0..90
  float acc[4][6] = {};
  const int prow = (y0 + y) * 96 + x0;

  for (int i = 0; i < 7; ++i) {
    float vrow[4][12];
    #pragma unroll
    for (int ch = 0; ch < 4; ++ch) {
      const unsigned int* lsrc = (const unsigned int*)&lv[(ch * 22 + (y + i)) * 104 + x0];
      #pragma unroll
      for (int t = 0; t < 6; ++t) {
        unsigned int u = lsrc[t];
        vrow[ch][2 * t]     = lo2f(u);
        vrow[ch][2 * t + 1] = hi2f(u);
      }
    }
    #pragma unroll
    for (int j = 0; j < 7; ++j) {
      const unsigned int* asrc = (const unsigned int*)
          &attn_c[((size_t)fc * 294 + head * 49 + i * 7 + j) * PIX + prow];
      unsigned int u0 = asrc[0], u1 = asrc[1], u2 = asrc[2];
      float av[6] = {lo2f(u0), hi2f(u0), lo2f(u1), hi2f(u1), lo2f(u2), hi2f(u2)};
      #pragma unroll
      for (int o = 0; o < 6; ++o)
        #pragma unroll
        for (int ch = 0; ch < 4; ++ch)
          acc[ch][o] += av[o] * vrow[ch][o + j];
    }
  }

  // blocked-4 store: 48B contiguous per thread.
  size_t obase = ((size_t)(f * 24 + cq) * PIX + prow) * 4;
  #pragma unroll
  for (int o = 0; o < 6; o += 2) {
    ushort8 r8;
    #pragma unroll
    for (int ch = 0; ch < 4; ++ch) {
      r8[ch]     = f2b(acc[ch][o]);
      r8[ch + 4] = f2b(acc[ch][o + 1]);
    }
    *(ushort8*)&out_t[obase + o * 4] = r8;
  }
}

extern "C" void kernel_launch(void* const* d_in, const int* in_sizes, int n_in,
                              void* d_out, int out_size, void* d_ws, size_t ws_size,
                              hipStream_t stream) {
  const float* x    = (const float*)d_in[0];
  const float* ln_g = (const float*)d_in[1];
  const float* ln_b = (const float*)d_in[2];
  const float* w_qk = (const float*)d_in[3];
  const float* b_qk = (const float*)d_in[4];
  const float* w_v  = (const float*)d_in[5];
  const float* b_v  = (const float*)d_in[6];
  const float* w_a1 = (const float*)d_in[7];
  const float* b_a1 = (const float*)d_in[8];
  const float* w_a2 = (const float*)d_in[9];
  const float* b_a2 = (const float*)d_in[10];
  const float* g_mul= (const float*)d_in[11];
  const float* g_add= (const float*)d_in[12];
  const float* w_p  = (const float*)d_in[13];
  const float* b_p  = (const float*)d_in[14];

  char* ws = (char*)d_ws;
  u16*   W2    = (u16*)(ws + 0);
  float* bias2 = (float*)(ws + 61440);
  u16*   WA2   = (u16*)(ws + 62720);
  float* biasA2= (float*)(ws + 124160);
  u16*   WP    = (u16*)(ws + 125440);
  float* biasP = (float*)(ws + 150016);
  float* WC1   = (float*)(ws + 150528);
  u16*   xn_t  = (u16*)(ws + 225792);       // reused as a_t
  u16*   hbuf  = (u16*)(ws + 28537344);     // reused as out_t
  u16*   vbuf  = (u16*)(ws + 56848896);
  u16*   attnc = (u16*)(ws + 85160448);     // 8-frame attn chunk (8 x 294 x 9216)

  k_prep<<<365, 256, 0, stream>>>(w_qk, b_qk, w_v, b_v, w_a1, w_a2, b_a2, g_mul, g_add,
                                  w_p, b_p, W2, bias2, WA2, biasA2, WP, biasP, WC1);
  k_ln<<<576, 256, 0, stream>>>(x, ln_g, ln_b, xn_t);
  k_gemm<0><<<dim3(144, 5, 16), 256, 0, stream>>>(xn_t, W2, bias2, hbuf, vbuf,
                                                  nullptr, nullptr, 0);
  k_conv<<<dim3(24, 6, 16), 256, 0, stream>>>(hbuf, WC1, b_a1, xn_t /*a_t*/);
  for (int c = 0; c < 2; ++c) {
    k_gemm<1><<<dim3(144, 5, 8), 256, 0, stream>>>(xn_t /*a_t*/, WA2, biasA2,
                                                   attnc, nullptr, nullptr, nullptr, c * 8);
    k_aggr<<<dim3(24, 6, 8), 256, 0, stream>>>(attnc, vbuf, hbuf /*out_t*/, c * 8);
  }
  k_gemm<2><<<dim3(144, 2, 16), 256, 0, stream>>>(hbuf /*out_t*/, WP, biasP,
                                                  nullptr, nullptr, (float*)d_out, x, 0);
}

// Round 4
// 395.005 us; speedup vs baseline: 1.1916x; 1.0335x over previous
//
#include <hip/hip_runtime.h>
#include <hip/hip_bf16.h>

// ELSA block. Inputs: float32. Output: float32. Internal: bf16 (MFMA) + f16 (conv).
// Pipeline:
//  k_prep: weight repack (interleave q/k rows, pad, fold ghost, pack conv w as f16 pairs)
//  k_ln:   LayerNorm, x (B,C,D,H,W) f32 -> xn_t (frame*pix, 96) bf16 [pixel-major]
//  k_gemm<0>: qkv projection (MFMA) -> h=(q*k*scale) (f,c,p) f16, v (f,c,p) bf16
//  k_conv: grouped 7x7 conv + exact GELU via v_dot2_f32_f16 -> a_t BLOCKED-4
//  2 chunks of 8 frames:  k_gemm<1>: 294-ch logits + ghost -> attn_c (8f,294,p)
//                         k_aggr: 49-tap window aggregation -> out_t BLOCKED-4
//                                 (XCD-swizzled: 4 cquads of a head co-resident)
//  k_gemm<2>: out proj + bias + f32 residual -> d_out f32 (B,C,D,H,W)
// Workspace (bytes), total 128,512,512 (~122.6 MB):
//  [0)        W2 (320x96 bf16)  61,440
//  [61440)    bias2 (320 f32)    1,280
//  [62720)    WA2 (320x96 bf16) 61,440
//  [124160)   biasA2 (320 f32)   1,280
//  [125440)   WP (128x96 bf16)  24,576
//  [150016)   biasP (128 f32)      512
//  [150528)   WCV (24x4x7x4x7 uint f16-pairs) 75,264
//  [225792)   xn_t / a_t   28,311,552
//  [28537344) h / out_t    28,311,552
//  [56848896) v            28,311,552
//  [85160448) attn_c (8x294x9216 bf16) 43,352,064

typedef unsigned short u16;
typedef short bf16x8 __attribute__((ext_vector_type(8)));
typedef float floatx4 __attribute__((ext_vector_type(4)));
typedef unsigned short ushort8 __attribute__((ext_vector_type(8)));
typedef unsigned short ushort4v __attribute__((ext_vector_type(4)));
typedef unsigned int uint4v __attribute__((ext_vector_type(4)));
typedef unsigned int uint2v __attribute__((ext_vector_type(2)));
typedef _Float16 f16x2 __attribute__((ext_vector_type(2)));

#define PIX      9216
#define SCALE_QK 0.25f

__device__ __forceinline__ float lo2f(unsigned int u) {
  union { unsigned int i; float f; } z; z.i = u << 16; return z.f;
}
__device__ __forceinline__ float hi2f(unsigned int u) {
  union { unsigned int i; float f; } z; z.i = u & 0xFFFF0000u; return z.f;
}
__device__ __forceinline__ u16 f2b(float f) {
  union { float f; unsigned int i; } z; z.f = f;
  unsigned int r = z.i + 0x7fffu + ((z.i >> 16) & 1u);
  return (u16)(r >> 16);
}
__device__ __forceinline__ u16 f2h(float f) {
  _Float16 h = (_Float16)f;
  union { _Float16 h; u16 u; } z; z.h = h; return z.u;
}
__device__ __forceinline__ f16x2 u2h(unsigned int u) {
  union { unsigned int u; f16x2 h; } z; z.u = u; return z.h;
}
__device__ __forceinline__ float dot2(unsigned int w, unsigned int x, float acc) {
#if __has_builtin(__builtin_amdgcn_fdot2)
  return __builtin_amdgcn_fdot2(u2h(w), u2h(x), acc, false);
#else
  f16x2 a = u2h(w), b = u2h(x);
  return acc + (float)a[0] * (float)b[0] + (float)a[1] * (float)b[1];
#endif
}

// ---------------- weight prep (f32 in, bf16/f16/f32 out) ----------------
__global__ void k_prep(const float* __restrict__ w_qk, const float* __restrict__ b_qk,
                       const float* __restrict__ w_v,  const float* __restrict__ b_v,
                       const float* __restrict__ w_a1,
                       const float* __restrict__ w_a2, const float* __restrict__ b_a2,
                       const float* __restrict__ g_mul,const float* __restrict__ g_add,
                       const float* __restrict__ w_p,  const float* __restrict__ b_p,
                       u16* __restrict__ W2, float* __restrict__ bias2,
                       u16* __restrict__ WA2, float* __restrict__ biasA2,
                       u16* __restrict__ WP, float* __restrict__ biasP,
                       unsigned int* __restrict__ WCV) {
  int i = blockIdx.x * 256 + threadIdx.x;
  if (i < 30720) {                       // W2: 320*96
    int r = i / 96, ci = i % 96;
    float val = 0.f;
    if (r < 192) { int src = (r & 1) ? (96 + (r >> 1)) : (r >> 1); val = w_qk[src * 96 + ci]; }
    else if (r < 288) val = w_v[(r - 192) * 96 + ci];
    W2[i] = f2b(val);
  } else if (i < 31040) {                // bias2: 320
    int r = i - 30720; float bv = 0.f;
    if (r < 192) { int src = (r & 1) ? (96 + (r >> 1)) : (r >> 1); bv = b_qk[src]; }
    else if (r < 288) bv = b_v[r - 192];
    bias2[r] = bv;
  } else if (i < 61760) {                // WA2: 320*96
    int j = i - 31040; int r = j / 96, ci = j % 96;
    float wv = 0.f;
    if (r < 294) wv = w_a2[r * 96 + ci] * g_mul[r];
    WA2[j] = f2b(wv);
  } else if (i < 62080) {                // biasA2: 320
    int r = i - 61760; float bv = 0.f;
    if (r < 294) bv = b_a2[r] * g_mul[r] + g_add[r];
    biasA2[r] = bv;
  } else if (i < 74368) {                // WP: 128*96
    int j = i - 62080; int r = j / 96;
    WP[j] = (r < 96) ? f2b(w_p[j]) : (u16)0;
  } else if (i < 74496) {                // biasP: 128
    int r = i - 74368;
    biasP[r] = (r < 96) ? b_p[r] : 0.f;
  } else if (i < 93312) {                // WCV: f16 pair table [g][ch][ky][co][7]
    int j = i - 74496;                   // 18816 uints
    int u = j % 7, co = (j / 7) & 3, ky = (j / 28) % 7, ch = (j / 196) & 3, g = j / 784;
    const float* wsrc = &w_a1[(g * 4 + co) * 196 + ch * 49 + ky * 7];
    // u0..2: E pairs (w0,w1)(w2,w3)(w4,w5); u3: (w6,0); u4..6: O pairs (w1,w2)(w3,w4)(w5,w6)
    float a, b;
    if (u < 3)       { a = wsrc[2 * u];     b = wsrc[2 * u + 1]; }
    else if (u == 3) { a = wsrc[6];         b = 0.f; }
    else             { int t = u - 3;       a = wsrc[2 * t - 1]; b = wsrc[2 * t]; }
    WCV[j] = (unsigned int)f2h(a) | ((unsigned int)f2h(b) << 16);
  }
}

// ---------------- LayerNorm ----------------
__global__ __launch_bounds__(256) void k_ln(const float* __restrict__ x,
                                            const float* __restrict__ lg,
                                            const float* __restrict__ lb,
                                            u16* __restrict__ xn) {
  int idx = blockIdx.x * 256 + threadIdx.x;    // 0..147455
  int f = idx / PIX, p = idx % PIX;
  int b = f >> 3, d = f & 7;
  size_t base = ((size_t)(b * 768 + d)) * PIX + p;  // + c*73728
  float s = 0.f, ss = 0.f;
  for (int c = 0; c < 96; ++c) {
    float v = x[base + (size_t)c * 73728];
    s += v; ss += v * v;
  }
  float mu = s * (1.f / 96.f);
  float var = ss * (1.f / 96.f) - mu * mu;
  float rs = rsqrtf(var + 1e-5f);
  size_t ob = (size_t)idx * 96;
  for (int c0 = 0; c0 < 96; c0 += 8) {
    ushort8 pack;
    for (int u = 0; u < 8; ++u) {
      int c = c0 + u;
      float v = x[base + (size_t)c * 73728];
      pack[u] = f2b((v - mu) * rs * lg[c] + lb[c]);
    }
    *(ushort8*)&xn[ob + c0] = pack;
  }
}

// ---------------- MFMA GEMM (64co x 64p tile, K=96) ----------------
// MODE 0: qkv -> h f16 (out0), v bf16 (out1), f = blockIdx.z. X = xn_t.
// MODE 1: attn chunk (out0, f = fArg + blockIdx.z, store frame-local z). X = a_t BLOCKED-4.
// MODE 2: final f32 (outF = d_out), resid = x f32, f = blockIdx.z. X = out_t BLOCKED-4.
template <int MODE>
__global__ __launch_bounds__(256) void k_gemm(const u16* __restrict__ X,
                                              const u16* __restrict__ W,
                                              const float* __restrict__ bias,
                                              u16* __restrict__ out0,
                                              u16* __restrict__ out1,
                                              float* __restrict__ outF,
                                              const float* __restrict__ resid,
                                              int fArg) {
  __shared__ u16 lw[64 * 104];
  __shared__ u16 lx[64 * 104];
  const int tid = threadIdx.x;
  const int fc = blockIdx.z;
  const int f = (MODE == 1) ? (fArg + fc) : fc;
  const int p0 = blockIdx.x * 64;
  const int cot = blockIdx.y;

  if constexpr (MODE == 0) {
    for (int ch = tid; ch < 768; ch += 256) {
      int r = ch / 12, s2 = ch % 12;
      *(uint4v*)&lw[r * 104 + s2 * 8] = *(const uint4v*)&W[(size_t)(cot * 64 + r) * 96 + s2 * 8];
      *(uint4v*)&lx[r * 104 + s2 * 8] = *(const uint4v*)&X[((size_t)(f * PIX + p0 + r)) * 96 + s2 * 8];
    }
  } else {
    for (int ch = tid; ch < 768; ch += 256) {
      int r = ch / 12, s2 = ch % 12;
      *(uint4v*)&lw[r * 104 + s2 * 8] = *(const uint4v*)&W[(size_t)(cot * 64 + r) * 96 + s2 * 8];
    }
    // X is blocked-4: X[((f*24 + g)*PIX + p)*4 + co]. Channel-oct s2 spans
    // groups 2*s2, 2*s2+1. r fastest across lanes -> contiguous 8B reads.
    for (int idx = tid; idx < 768; idx += 256) {
      int s2 = idx >> 6, r = idx & 63;
      const u16* src0 = &X[((size_t)(f * 24 + 2 * s2) * PIX + p0 + r) * 4];
      const u16* src1 = &X[((size_t)(f * 24 + 2 * s2 + 1) * PIX + p0 + r) * 4];
      *(uint2v*)&lx[r * 104 + s2 * 8]     = *(const uint2v*)src0;
      *(uint2v*)&lx[r * 104 + s2 * 8 + 4] = *(const uint2v*)src1;
    }
  }
  __syncthreads();

  const int lane = tid & 63, wv = tid >> 6;
  const int cw = (wv >> 1) * 32, pw = (wv & 1) * 32;
  const int m = lane & 15, quad = lane >> 4;

  floatx4 acc[2][2] = {};
  for (int ks = 0; ks < 3; ++ks) {
    int ko = ks * 32 + quad * 8;
    bf16x8 a0 = *(const bf16x8*)&lw[(cw + m) * 104 + ko];
    bf16x8 a1 = *(const bf16x8*)&lw[(cw + 16 + m) * 104 + ko];
    bf16x8 b0 = *(const bf16x8*)&lx[(pw + m) * 104 + ko];
    bf16x8 b1 = *(const bf16x8*)&lx[(pw + 16 + m) * 104 + ko];
    acc[0][0] = __builtin_amdgcn_mfma_f32_16x16x32_bf16(a0, b0, acc[0][0], 0, 0, 0);
    acc[0][1] = __builtin_amdgcn_mfma_f32_16x16x32_bf16(a0, b1, acc[0][1], 0, 0, 0);
    acc[1][0] = __builtin_amdgcn_mfma_f32_16x16x32_bf16(a1, b0, acc[1][0], 0, 0, 0);
    acc[1][1] = __builtin_amdgcn_mfma_f32_16x16x32_bf16(a1, b1, acc[1][1], 0, 0, 0);
  }

  for (int mt = 0; mt < 2; ++mt)
    for (int nt = 0; nt < 2; ++nt) {
      int R = cot * 64 + cw + mt * 16 + quad * 4;
      int pc = p0 + pw + nt * 16 + m;
      floatx4 v4 = acc[mt][nt];
      if (MODE == 0) {
        if (cot < 3) {
          float q0 = v4[0] + bias[R + 0], k0 = v4[1] + bias[R + 1];
          float q1 = v4[2] + bias[R + 2], k1 = v4[3] + bias[R + 3];
          int hc = R >> 1;
          out0[((size_t)f * 96 + hc) * PIX + pc]     = f2h(q0 * k0 * SCALE_QK);
          out0[((size_t)f * 96 + hc + 1) * PIX + pc] = f2h(q1 * k1 * SCALE_QK);
        } else {
          for (int r = 0; r < 4; ++r) {
            int vr = R + r - 192;
            if (vr < 96) out1[((size_t)f * 96 + vr) * PIX + pc] = f2b(v4[r] + bias[R + r]);
          }
        }
      } else if (MODE == 1) {
        for (int r = 0; r < 4; ++r) {
          int o = R + r;
          if (o < 294) out0[((size_t)fc * 294 + o) * PIX + pc] = f2b(v4[r] + bias[o]);
        }
      } else {
        int b = f >> 3, d = f & 7;
        for (int r = 0; r < 4; ++r) {
          int o = R + r;
          if (o < 96) {
            size_t gi = ((size_t)(b * 96 + o) * 8 + d) * PIX + pc;
            outF[gi] = resid[gi] + v4[r] + bias[o];
          }
        }
      }
    }
}

// ---------------- grouped 7x7 conv + GELU (f16 dot2, sliding window) ----------
// h: (f, 96, 9216) f16 -> a_t BLOCKED-4: a_t[((f*24+g)*PIX + pix)*4 + co].
// block = (group g of 4 ch, 16-row tile, frame). thread = (y of 16, xseg of 6).
// LDS image: 4ch x 22 rows x 104 cols u16, col = ax+4 (left pad 4 -> all dword aligned).
// Inner loop: v_dot2_f32_f16, weight pairs from WCV (E/O phase tables), no unpacking.
__global__ __launch_bounds__(256, 4) void k_conv(const u16* __restrict__ h,
                                                 const unsigned int* __restrict__ wcv,
                                                 const float* __restrict__ b_a1,
                                                 u16* __restrict__ a_t) {
  __shared__ u16 li[4 * 22 * 104];   // 18.3KB
  const int g = blockIdx.x, ty = blockIdx.y, f = blockIdx.z;
  const int tid = threadIdx.x;
  const int gb = g * 4, y0 = ty * 16;
  // dword staging: 4ch x 22 rows x 52 dwords; dword jd covers ax = 2jd-4, 2jd-3.
  // valid image dwords are exactly jd in [2,49] (ax 0..95), no straddle.
  for (int idx = tid; idx < 4576; idx += 256) {
    int row = idx / 52;            // ch*22 + rr
    int jd  = idx - row * 52;
    int ch  = row / 22;
    int rr  = row - ch * 22;
    int ay  = y0 - 3 + rr;
    unsigned int val = 0;
    if (jd >= 2 && jd <= 49 && ay >= 0 && ay < 96)
      val = *(const unsigned int*)&h[((size_t)f * 96 + gb + ch) * PIX + ay * 96 + (2 * jd - 4)];
    *(unsigned int*)&li[row * 104 + 2 * jd] = val;
  }
  __syncthreads();

  const int y = tid >> 4;            // 0..15
  const int x0 = (tid & 15) * 6;     // 0..90
  float acc[4][6];
  #pragma unroll
  for (int co = 0; co < 4; ++co) {
    float bv = b_a1[gb + co];
    #pragma unroll
    for (int o = 0; o < 6; ++o) acc[co][o] = bv;
  }

  for (int ch = 0; ch < 4; ++ch)
    for (int ky = 0; ky < 7; ++ky) {
      const unsigned int* wrow = &wcv[(((g * 4 + ch) * 7) + ky) * 28];
      const unsigned int* lsrc =
          (const unsigned int*)&li[(ch * 22 + (y + ky)) * 104 + x0];
      unsigned int IN[7];
      #pragma unroll
      for (int t = 0; t < 7; ++t) IN[t] = lsrc[t];
      #pragma unroll
      for (int co = 0; co < 4; ++co) {
        unsigned int w0 = wrow[co * 7 + 0], w1 = wrow[co * 7 + 1];
        unsigned int w2 = wrow[co * 7 + 2], w3 = wrow[co * 7 + 3];
        unsigned int w4 = wrow[co * 7 + 4], w5 = wrow[co * 7 + 5];
        unsigned int w6 = wrow[co * 7 + 6];
        unsigned int o0 = w0 << 16;   // (0, w_first)
        float a;
        a = acc[co][0]; a = dot2(o0, IN[0], a); a = dot2(w4, IN[1], a);
                        a = dot2(w5, IN[2], a); a = dot2(w6, IN[3], a); acc[co][0] = a;
        a = acc[co][1]; a = dot2(w0, IN[1], a); a = dot2(w1, IN[2], a);
                        a = dot2(w2, IN[3], a); a = dot2(w3, IN[4], a); acc[co][1] = a;
        a = acc[co][2]; a = dot2(o0, IN[1], a); a = dot2(w4, IN[2], a);
                        a = dot2(w5, IN[3], a); a = dot2(w6, IN[4], a); acc[co][2] = a;
        a = acc[co][3]; a = dot2(w0, IN[2], a); a = dot2(w1, IN[3], a);
                        a = dot2(w2, IN[4], a); a = dot2(w3, IN[5], a); acc[co][3] = a;
        a = acc[co][4]; a = dot2(o0, IN[2], a); a = dot2(w4, IN[3], a);
                        a = dot2(w5, IN[4], a); a = dot2(w6, IN[5], a); acc[co][4] = a;
        a = acc[co][5]; a = dot2(w0, IN[3], a); a = dot2(w1, IN[4], a);
                        a = dot2(w2, IN[5], a); a = dot2(w3, IN[6], a); acc[co][5] = a;
      }
    }

  // blocked-4 store: 48B contiguous per thread, full-line coalesced per wave.
  size_t obase = ((size_t)(f * 24 + g) * PIX + (size_t)(y0 + y) * 96 + x0) * 4;
  #pragma unroll
  for (int o = 0; o < 6; o += 2) {
    ushort8 r8;
    #pragma unroll
    for (int co = 0; co < 4; ++co) {
      float a0 = acc[co][o], a1 = acc[co][o + 1];
      r8[co]     = f2b(0.5f * a0 * (1.f + erff(a0 * 0.70710678118f)));
      r8[co + 4] = f2b(0.5f * a1 * (1.f + erff(a1 * 0.70710678118f)));
    }
    *(ushort8*)&a_t[obase + o * 4] = r8;
  }
}

// ---------------- 49-tap window aggregation (8-frame chunk) ----------------
// attn_c: (8, 294, 9216) bf16, v: (f, 96, 9216) bf16 -> out_t BLOCKED-4:
// out_t[((f*24+cq)*PIX + pix)*4 + ch].
// XCD swizzle: the 4 cquads sharing one head's 49 attn planes get the same
// wgid%8 (same XCD under round-robin dispatch) and adjacent dispatch slots,
// so attn_c re-reads hit that XCD's L2 instead of HBM.
// Bijection: 1152 = 8 xcd * 4 member * 36 slot.
__global__ __launch_bounds__(256, 4) void k_aggr(const u16* __restrict__ attn_c,
                                                 const u16* __restrict__ v,
                                                 u16* __restrict__ out_t,
                                                 int fbase) {
  __shared__ u16 lv[4 * 22 * 104];   // 18.3KB
  const int wgid = blockIdx.x + 24 * (blockIdx.y + 6 * blockIdx.z);
  const int xcd = wgid & 7;
  const int member = (wgid >> 3) & 3;
  const int slot = wgid >> 5;
  const int gidx = slot * 8 + xcd;       // 0..287
  const int cqh = gidx % 6;
  const int ty = (gidx / 6) % 6;
  const int fc = gidx / 36;
  const int cq = cqh * 4 + member;
  const int f = fbase + fc;
  const int tid = threadIdx.x;
  const int c0 = cq * 4, y0 = ty * 16;
  const int head = c0 >> 4;
  for (int idx = tid; idx < 4 * 22 * 104; idx += 256) {
    int col = idx % 104;
    int rr = (idx / 104) % 22;
    int ch = idx / (104 * 22);
    int ax = col - 3, ay = y0 - 3 + rr;
    u16 val = 0;
    if (ax >= 0 && ax < 96 && ay >= 0 && ay < 96)
      val = v[((size_t)f * 96 + c0 + ch) * PIX + ay * 96 + ax];
    lv[idx] = val;
  }
  __syncthreads();

  const int y = tid >> 4;            // 0..15
  const int x0 = (tid & 15) * 6;     // 0..90
  float acc[4][6] = {};
  const int prow = (y0 + y) * 96 + x0;

  for (int i = 0; i < 7; ++i) {
    float vrow[4][12];
    #pragma unroll
    for (int ch = 0; ch < 4; ++ch) {
      const unsigned int* lsrc = (const unsigned int*)&lv[(ch * 22 + (y + i)) * 104 + x0];
      #pragma unroll
      for (int t = 0; t < 6; ++t) {
        unsigned int u = lsrc[t];
        vrow[ch][2 * t]     = lo2f(u);
        vrow[ch][2 * t + 1] = hi2f(u);
      }
    }
    #pragma unroll
    for (int j = 0; j < 7; ++j) {
      const unsigned int* asrc = (const unsigned int*)
          &attn_c[((size_t)fc * 294 + head * 49 + i * 7 + j) * PIX + prow];
      unsigned int u0 = asrc[0], u1 = asrc[1], u2 = asrc[2];
      float av[6] = {lo2f(u0), hi2f(u0), lo2f(u1), hi2f(u1), lo2f(u2), hi2f(u2)};
      #pragma unroll
      for (int o = 0; o < 6; ++o)
        #pragma unroll
        for (int ch = 0; ch < 4; ++ch)
          acc[ch][o] += av[o] * vrow[ch][o + j];
    }
  }

  // blocked-4 store: 48B contiguous per thread.
  size_t obase = ((size_t)(f * 24 + cq) * PIX + prow) * 4;
  #pragma unroll
  for (int o = 0; o < 6; o += 2) {
    ushort8 r8;
    #pragma unroll
    for (int ch = 0; ch < 4; ++ch) {
      r8[ch]     = f2b(acc[ch][o]);
      r8[ch + 4] = f2b(acc[ch][o + 1]);
    }
    *(ushort8*)&out_t[obase + o * 4] = r8;
  }
}

extern "C" void kernel_launch(void* const* d_in, const int* in_sizes, int n_in,
                              void* d_out, int out_size, void* d_ws, size_t ws_size,
                              hipStream_t stream) {
  const float* x    = (const float*)d_in[0];
  const float* ln_g = (const float*)d_in[1];
  const float* ln_b = (const float*)d_in[2];
  const float* w_qk = (const float*)d_in[3];
  const float* b_qk = (const float*)d_in[4];
  const float* w_v  = (const float*)d_in[5];
  const float* b_v  = (const float*)d_in[6];
  const float* w_a1 = (const float*)d_in[7];
  const float* b_a1 = (const float*)d_in[8];
  const float* w_a2 = (const float*)d_in[9];
  const float* b_a2 = (const float*)d_in[10];
  const float* g_mul= (const float*)d_in[11];
  const float* g_add= (const float*)d_in[12];
  const float* w_p  = (const float*)d_in[13];
  const float* b_p  = (const float*)d_in[14];

  char* ws = (char*)d_ws;
  u16*   W2    = (u16*)(ws + 0);
  float* bias2 = (float*)(ws + 61440);
  u16*   WA2   = (u16*)(ws + 62720);
  float* biasA2= (float*)(ws + 124160);
  u16*   WP    = (u16*)(ws + 125440);
  float* biasP = (float*)(ws + 150016);
  unsigned int* WCV = (unsigned int*)(ws + 150528);
  u16*   xn_t  = (u16*)(ws + 225792);       // reused as a_t
  u16*   hbuf  = (u16*)(ws + 28537344);     // reused as out_t
  u16*   vbuf  = (u16*)(ws + 56848896);
  u16*   attnc = (u16*)(ws + 85160448);     // 8-frame attn chunk (8 x 294 x 9216)

  k_prep<<<365, 256, 0, stream>>>(w_qk, b_qk, w_v, b_v, w_a1, w_a2, b_a2, g_mul, g_add,
                                  w_p, b_p, W2, bias2, WA2, biasA2, WP, biasP, WCV);
  k_ln<<<576, 256, 0, stream>>>(x, ln_g, ln_b, xn_t);
  k_gemm<0><<<dim3(144, 5, 16), 256, 0, stream>>>(xn_t, W2, bias2, hbuf, vbuf,
                                                  nullptr, nullptr, 0);
  k_conv<<<dim3(24, 6, 16), 256, 0, stream>>>(hbuf, WCV, b_a1, xn_t /*a_t*/);
  for (int c = 0; c < 2; ++c) {
    k_gemm<1><<<dim3(144, 5, 8), 256, 0, stream>>>(xn_t /*a_t*/, WA2, biasA2,
                                                   attnc, nullptr, nullptr, nullptr, c * 8);
    k_aggr<<<dim3(24, 6, 8), 256, 0, stream>>>(attnc, vbuf, hbuf /*out_t*/, c * 8);
  }
  k_gemm<2><<<dim3(144, 2, 16), 256, 0, stream>>>(hbuf /*out_t*/, WP, biasP,
                                                  nullptr, nullptr, (float*)d_out, x, 0);
}